// Round 16
// baseline (499.207 us; speedup 1.0000x reference)
//
#include <hip/hip_runtime.h>
#include <float.h>

// AttentionAgg via destination-CSR (no float atomics).
//   score = M @ a; smax = segmax(score,dest); ex = exp(score-smax[dest])
//   denom = segsum(ex,dest); alpha = ex/denom[dest]
//   Mv = segsum(alpha*M, dest); out = Mv[src] - alpha[rev]*M[rev]
//
// E = 800000, d = 64, N = 50000 (dim_size device scalar; hardcoded).
//
// Round-15 -> 16: micro-opts of the gather kernels are exhausted (ILP
// neutral, bf16 neutral, prefetch worse, fused-score worse). Remaining
// lever is the ACCESS PATTERN: k_out's 205MB random gather of M[rev].
// Rewrite k_out in rev-major order: build a rev-CSR (buckets over rev
// values, reusing hist/alloc/fill) and for each q stream M[q]/alpha[q]
// SEQUENTIALLY, gather only L3-resident Mv[src], and scatter nontemporal
// out[e] writes. Randomness moves from a stalling read to a fire-and-
// forget write. All other kernels are byte-identical round-9 (259us).

#define THREADS 256

typedef float f32x4 __attribute__((ext_vector_type(4)));

// ---------------------------------------------------------------------------
// K0: zero p[0..n4) int4s.
__global__ void k_zero(int4* __restrict__ p, int n4) {
    int i = blockIdx.x * blockDim.x + threadIdx.x;
    if (i < n4) p[i] = make_int4(0, 0, 0, 0);
}

// ---------------------------------------------------------------------------
// K1: histogram of idx[] (generic; used for dest->counts and rev->counts2).
__global__ void k_hist(const int* __restrict__ idx,
                       int* __restrict__ counts, int E) {
    int e = blockIdx.x * blockDim.x + threadIdx.x;
    if (e >= E) return;
    atomicAdd(&counts[idx[e]], 1);
}

// ---------------------------------------------------------------------------
// K2: range allocation (generic over NB buckets). Wave prefix + one
// atomicAdd(total) per wave -> offsets[n], cursor[n].
__global__ void k_alloc(const int* __restrict__ counts,
                        int* __restrict__ total,
                        int* __restrict__ offsets,
                        int* __restrict__ cursor,
                        int NB) {
    int n    = blockIdx.x * blockDim.x + threadIdx.x;
    int lane = threadIdx.x & 63;
    int c = (n < NB) ? counts[n] : 0;
    int x = c;
    #pragma unroll
    for (int off = 1; off < 64; off <<= 1) {
        int y = __shfl_up(x, off, 64);
        if (lane >= off) x += y;
    }
    int wsum = __shfl(x, 63, 64);
    int base = 0;
    if (lane == 63) base = atomicAdd(total, wsum);
    base = __shfl(base, 63, 64);
    if (n < NB) {
        int my = base + x - c;                 // exclusive position
        offsets[n] = my;
        cursor[n]  = my;
    }
}

// ---------------------------------------------------------------------------
// K3: bucket fill (generic): sorted[cursor[idx[e]]++] = e.
__global__ void k_fill(const int* __restrict__ idx,
                       int* __restrict__ cursor,
                       int* __restrict__ sorted,
                       int E) {
    int e = blockIdx.x * blockDim.x + threadIdx.x;
    if (e >= E) return;
    int pos = atomicAdd(&cursor[idx[e]], 1);
    sorted[pos] = e;
}

// ---------------------------------------------------------------------------
// K4: fused score + dest-CSR fill. 16 lanes/edge, float4 loads (streams M).
// lane0: pos = cursor[dest]++; writes sorted_eid & sorted_score.
__global__ void k_score_fill(const float4* __restrict__ M4,
                             const float4* __restrict__ a4,
                             const int* __restrict__ dest,
                             int* __restrict__ cursor,
                             int* __restrict__ sorted_eid,
                             float* __restrict__ sorted_score,
                             int E) {
    long long gid = (long long)blockIdx.x * blockDim.x + threadIdx.x;
    int e  = (int)(gid >> 4);
    int sl = (int)(gid & 15);
    if (e >= E) return;
    float4 m  = M4[(size_t)e * 16 + sl];
    float4 av = a4[sl];                        // 256B, L1-resident
    float v = m.x * av.x + m.y * av.y + m.z * av.z + m.w * av.w;
    v += __shfl_xor(v, 1, 64);
    v += __shfl_xor(v, 2, 64);
    v += __shfl_xor(v, 4, 64);
    v += __shfl_xor(v, 8, 64);
    if (sl == 0) {
        int pos = atomicAdd(&cursor[dest[e]], 1);
        sorted_eid[pos]   = e;
        sorted_score[pos] = v;
    }
}

// ---------------------------------------------------------------------------
// K5: one wave per node; writes Mv row AND per-edge alpha. (round-9 body)
__global__ void k_aggregate(const float4* __restrict__ M4,
                            const float* __restrict__ sorted_score,
                            const int* __restrict__ sorted_eid,
                            const int* __restrict__ offsets,
                            const int* __restrict__ counts,
                            float4* __restrict__ Mv4,
                            float* __restrict__ alpha,
                            int N) {
    long long gid = (long long)blockIdx.x * blockDim.x + threadIdx.x;
    int n    = (int)(gid >> 6);
    int lane = (int)(gid & 63);
    if (n >= N) return;
    int beg = offsets[n];
    int deg = counts[n];
    int end = beg + deg;
    int grp = lane >> 4;
    int sl  = lane & 15;

    float4 acc = make_float4(0.f, 0.f, 0.f, 0.f);

    if (deg <= 64) {
        int   eid = 0;
        float sc  = -FLT_MAX;
        if (lane < deg) {
            eid = sorted_eid[beg + lane];      // coalesced
            sc  = sorted_score[beg + lane];    // coalesced
        }
        float m = sc;
        #pragma unroll
        for (int off = 32; off; off >>= 1)
            m = fmaxf(m, __shfl_xor(m, off, 64));
        float exr = (lane < deg) ? expf(sc - m) : 0.f;
        float ds  = exr;
        #pragma unroll
        for (int off = 32; off; off >>= 1)
            ds += __shfl_xor(ds, off, 64);
        float inv = ds > 0.f ? 1.0f / ds : 0.0f;
        if (lane < deg) alpha[eid] = exr * inv;     // fused k_alpha
        // wave-uniform trip count; shfl src lane i = grp+4k <= 63, active.
        int iters = (deg + 3) >> 2;
        for (int k = 0; k < iters; ++k) {
            int i = grp + 4 * k;
            float ex = __shfl(exr, i, 64);
            int   e  = __shfl(eid, i, 64);
            if (i < deg) {
                float4 mm = M4[(size_t)e * 16 + sl];
                acc.x += ex * mm.x;
                acc.y += ex * mm.y;
                acc.z += ex * mm.z;
                acc.w += ex * mm.w;
            }
        }
        acc.x += __shfl_xor(acc.x, 16, 64);  acc.x += __shfl_xor(acc.x, 32, 64);
        acc.y += __shfl_xor(acc.y, 16, 64);  acc.y += __shfl_xor(acc.y, 32, 64);
        acc.z += __shfl_xor(acc.z, 16, 64);  acc.z += __shfl_xor(acc.z, 32, 64);
        acc.w += __shfl_xor(acc.w, 16, 64);  acc.w += __shfl_xor(acc.w, 32, 64);
        if (lane < 16) {
            float4 o;
            o.x = acc.x * inv; o.y = acc.y * inv;
            o.z = acc.z * inv; o.w = acc.w * inv;
            Mv4[(size_t)n * 16 + lane] = o;
        }
    } else {
        float m = -FLT_MAX;
        for (int i = beg + lane; i < end; i += 64)
            m = fmaxf(m, sorted_score[i]);
        #pragma unroll
        for (int off = 32; off; off >>= 1)
            m = fmaxf(m, __shfl_xor(m, off, 64));
        float dsum = 0.f;
        for (int i = beg + grp; i < end; i += 4) {
            int e = sorted_eid[i];
            float ex = expf(sorted_score[i] - m);
            if (sl == 0) dsum += ex;
            float4 mm = M4[(size_t)e * 16 + sl];
            acc.x += ex * mm.x;
            acc.y += ex * mm.y;
            acc.z += ex * mm.z;
            acc.w += ex * mm.w;
        }
        dsum += __shfl_xor(dsum, 16, 64);
        dsum += __shfl_xor(dsum, 32, 64);
        float dtot = __shfl(dsum, 0, 64);
        float inv = dtot > 0.f ? 1.0f / dtot : 0.0f;
        for (int i = beg + lane; i < end; i += 64)
            alpha[sorted_eid[i]] = expf(sorted_score[i] - m) * inv;
        acc.x += __shfl_xor(acc.x, 16, 64);  acc.x += __shfl_xor(acc.x, 32, 64);
        acc.y += __shfl_xor(acc.y, 16, 64);  acc.y += __shfl_xor(acc.y, 32, 64);
        acc.z += __shfl_xor(acc.z, 16, 64);  acc.z += __shfl_xor(acc.z, 32, 64);
        acc.w += __shfl_xor(acc.w, 16, 64);  acc.w += __shfl_xor(acc.w, 32, 64);
        if (lane < 16) {
            float4 o;
            o.x = acc.x * inv; o.y = acc.y * inv;
            o.z = acc.z * inv; o.w = acc.w * inv;
            Mv4[(size_t)n * 16 + lane] = o;
        }
    }
}

// ---------------------------------------------------------------------------
// K6: rev-major out. One 16-lane group per q in [0,E):
//   for each e with rev[e]==q: out[e] = Mv[src[e]] - alpha[q]*M[q].
// M[q]/alpha[q]/counts2[q] are SEQUENTIAL streams; Mv[src] gathers hit the
// 12.8MB L3-resident buffer; out[e] rows are scattered nontemporal stores
// (no dependent consumer -> no stall). Empty buckets (P=0.37) skip early.
__global__ void k_out_rev(const float4* __restrict__ M4,
                          const float4* __restrict__ Mv4,
                          const float* __restrict__ alpha,
                          const int* __restrict__ src,
                          const int* __restrict__ counts2,
                          const int* __restrict__ offsets2,
                          const int* __restrict__ sorted2,
                          f32x4* __restrict__ out4,
                          int E) {
    long long gid = (long long)blockIdx.x * blockDim.x + threadIdx.x;
    int q  = (int)(gid >> 4);
    int sl = (int)(gid & 15);
    if (q >= E) return;
    int d2 = counts2[q];                       // sequential (broadcast)
    if (d2 == 0) return;
    float  al = alpha[q];                      // sequential
    float4 mq = M4[(size_t)q * 16 + sl];       // sequential 256B row
    float4 am;                                 // alpha*M[q], reused per e
    am.x = al * mq.x; am.y = al * mq.y;
    am.z = al * mq.z; am.w = al * mq.w;
    int base = offsets2[q];
    for (int j = 0; j < d2; ++j) {
        int e = sorted2[base + j];
        int s = src[e];
        float4 mv = Mv4[(size_t)s * 16 + sl];  // L3-resident gather
        f32x4 o;
        o.x = mv.x - am.x;
        o.y = mv.y - am.y;
        o.z = mv.z - am.z;
        o.w = mv.w - am.w;
        __builtin_nontemporal_store(o, &out4[(size_t)e * 16 + sl]);
    }
}

// ---------------------------------------------------------------------------
extern "C" void kernel_launch(void* const* d_in, const int* in_sizes, int n_in,
                              void* d_out, int out_size, void* d_ws, size_t ws_size,
                              hipStream_t stream) {
    const float* M  = (const float*)d_in[0];
    const float* a  = (const float*)d_in[1];
    const int* eidx = (const int*)d_in[2];   // [2, E] flat: src row, dest row
    const int* rev  = (const int*)d_in[3];
    const int N = 50000;
    const int E = in_sizes[3];

    const int* src  = eidx;
    const int* dest = eidx + E;

    // Workspace:
    //  Mv[N*64] | sorted_score[E] | alpha[E] | sorted_eid[E] |
    //  counts[N]+total+total2+pad | offsets[N] | cursor[N] |
    //  counts2[E] | offsets2[E] | cursor2[E] | sorted2[E]     ~= 36 MB
    char* ws = (char*)d_ws;
    float* Mv           = (float*)ws; ws += (size_t)N * 64 * 4;
    float* sorted_score = (float*)ws; ws += (size_t)E * 4;
    float* alpha        = (float*)ws; ws += (size_t)E * 4;
    int*   sorted_eid   = (int*)ws;   ws += (size_t)E * 4;
    int*   counts       = (int*)ws;   ws += (size_t)(N + 4) * 4;  // +totals
    int*   offsets      = (int*)ws;   ws += (size_t)N * 4;
    int*   cursor       = (int*)ws;   ws += (size_t)N * 4;
    int*   counts2      = (int*)ws;   ws += (size_t)E * 4;
    int*   offsets2     = (int*)ws;   ws += (size_t)E * 4;
    int*   cursor2      = (int*)ws;   ws += (size_t)E * 4;
    int*   sorted2      = (int*)ws;   ws += (size_t)E * 4;
    int*   total        = counts + N;
    int*   total2       = counts + N + 1;

    long long tE16 = (long long)E * 16;
    int blocksE16 = (int)((tE16 + THREADS - 1) / THREADS);
    int blocksE   = (E + THREADS - 1) / THREADS;
    int blocksN   = (N + THREADS - 1) / THREADS;
    int blocksN64 = (int)(((long long)N * 64 + THREADS - 1) / THREADS);
    int n4        = (N + 4) / 4;               // counts + totals
    int blocksZ   = (n4 + THREADS - 1) / THREADS;
    int e4        = E / 4;                     // E multiple of 4
    int blocksZ2  = (e4 + THREADS - 1) / THREADS;

    // dest-CSR + scores (round-9 path)
    k_zero<<<blocksZ, THREADS, 0, stream>>>((int4*)counts, n4);
    k_zero<<<blocksZ2, THREADS, 0, stream>>>((int4*)counts2, e4);
    k_hist<<<blocksE, THREADS, 0, stream>>>(dest, counts, E);
    k_hist<<<blocksE, THREADS, 0, stream>>>(rev, counts2, E);
    k_alloc<<<blocksN, THREADS, 0, stream>>>(counts, total, offsets, cursor, N);
    k_alloc<<<blocksE, THREADS, 0, stream>>>(counts2, total2, offsets2, cursor2, E);
    k_score_fill<<<blocksE16, THREADS, 0, stream>>>(
        (const float4*)M, (const float4*)a, dest, cursor,
        sorted_eid, sorted_score, E);
    k_fill<<<blocksE, THREADS, 0, stream>>>(rev, cursor2, sorted2, E);
    k_aggregate<<<blocksN64, THREADS, 0, stream>>>(
        (const float4*)M, sorted_score, sorted_eid, offsets, counts,
        (float4*)Mv, alpha, N);
    k_out_rev<<<blocksE16, THREADS, 0, stream>>>(
        (const float4*)M, (const float4*)Mv, alpha, src,
        counts2, offsets2, sorted2, (f32x4*)d_out, E);
}

// Round 17
// 258.901 us; speedup vs baseline: 1.9282x; 1.9282x over previous
//
#include <hip/hip_runtime.h>
#include <float.h>

// AttentionAgg via destination-CSR (no float atomics).
//   score = M @ a; smax = segmax(score,dest); ex = exp(score-smax[dest])
//   denom = segsum(ex,dest); alpha = ex/denom[dest]
//   Mv = segsum(alpha*M, dest); out = Mv[src] - alpha[rev]*M[rev]
//
// E = 800000, d = 64, N = 50000 (dim_size device scalar; hardcoded).
//
// Round 17: byte-identical restore of the round-9 best (259.2us).
// Falsified since: ILP blocking (r11 neutral), bf16 gathers (r12 neutral),
// cooperative mega-kernel (r13, 5x worse), score-fused aggregate (r14
// neutral), register prefetch (r15, -47us), rev-major out + rev-CSR (r16,
// k_alloc over E serialized on one atomic counter, -240us). Conclusion:
// the two 205MB random-row-gather passes run at the machine's practical
// scattered-gather throughput; this structure is at its pattern floor.

#define THREADS 256

typedef float f32x4 __attribute__((ext_vector_type(4)));

// ---------------------------------------------------------------------------
// K0: zero counts[N] + total counter (N+4 ints, multiple of 4).
__global__ void k_zero(int4* __restrict__ p, int n4) {
    int i = blockIdx.x * blockDim.x + threadIdx.x;
    if (i < n4) p[i] = make_int4(0, 0, 0, 0);
}

// ---------------------------------------------------------------------------
// K1: histogram of dest (reads 3.2MB only).
__global__ void k_hist(const int* __restrict__ dest,
                       int* __restrict__ counts, int E) {
    int e = blockIdx.x * blockDim.x + threadIdx.x;
    if (e >= E) return;
    atomicAdd(&counts[dest[e]], 1);
}

// ---------------------------------------------------------------------------
// K2: range allocation. Wave-level exclusive prefix over counts + one
// atomicAdd(total) per wave -> offsets[n], cursor[n].
__global__ void k_alloc(const int* __restrict__ counts,
                        int* __restrict__ total,
                        int* __restrict__ offsets,
                        int* __restrict__ cursor,
                        int N) {
    int n    = blockIdx.x * blockDim.x + threadIdx.x;
    int lane = threadIdx.x & 63;
    int c = (n < N) ? counts[n] : 0;
    int x = c;
    #pragma unroll
    for (int off = 1; off < 64; off <<= 1) {
        int y = __shfl_up(x, off, 64);
        if (lane >= off) x += y;
    }
    int wsum = __shfl(x, 63, 64);
    int base = 0;
    if (lane == 63) base = atomicAdd(total, wsum);
    base = __shfl(base, 63, 64);
    if (n < N) {
        int my = base + x - c;                 // exclusive position
        offsets[n] = my;
        cursor[n]  = my;
    }
}

// ---------------------------------------------------------------------------
// K3: fused score + bucket fill. 16 lanes/edge, float4 loads.
// score = dot(M[e,:], a); lane0: pos = cursor[dest]++; write sorted_eid[pos]
// and sorted_score[pos].
__global__ void k_score_fill(const float4* __restrict__ M4,
                             const float4* __restrict__ a4,
                             const int* __restrict__ dest,
                             int* __restrict__ cursor,
                             int* __restrict__ sorted_eid,
                             float* __restrict__ sorted_score,
                             int E) {
    long long gid = (long long)blockIdx.x * blockDim.x + threadIdx.x;
    int e  = (int)(gid >> 4);
    int sl = (int)(gid & 15);
    if (e >= E) return;
    float4 m  = M4[(size_t)e * 16 + sl];
    float4 av = a4[sl];                        // 256B, L1-resident
    float v = m.x * av.x + m.y * av.y + m.z * av.z + m.w * av.w;
    v += __shfl_xor(v, 1, 64);
    v += __shfl_xor(v, 2, 64);
    v += __shfl_xor(v, 4, 64);
    v += __shfl_xor(v, 8, 64);
    if (sl == 0) {
        int pos = atomicAdd(&cursor[dest[e]], 1);
        sorted_eid[pos]   = e;
        sorted_score[pos] = v;
    }
}

// ---------------------------------------------------------------------------
// K4: one wave per node; writes Mv row AND per-edge alpha.
// Fast path (deg<=64): lane loads (eid, score) COALESCED from the sorted
// arrays; wave-reduce max and exp-sum in registers; weighted pass uses a
// WAVE-UNIFORM trip count so every __shfl executes with all lanes active
// (round-5 lesson). Fallback (deg>64): two-pass, also on sorted arrays.
__global__ void k_aggregate(const float4* __restrict__ M4,
                            const float* __restrict__ sorted_score,
                            const int* __restrict__ sorted_eid,
                            const int* __restrict__ offsets,
                            const int* __restrict__ counts,
                            float4* __restrict__ Mv4,
                            float* __restrict__ alpha,
                            int N) {
    long long gid = (long long)blockIdx.x * blockDim.x + threadIdx.x;
    int n    = (int)(gid >> 6);
    int lane = (int)(gid & 63);
    if (n >= N) return;
    int beg = offsets[n];
    int deg = counts[n];
    int end = beg + deg;
    int grp = lane >> 4;
    int sl  = lane & 15;

    float4 acc = make_float4(0.f, 0.f, 0.f, 0.f);

    if (deg <= 64) {
        int   eid = 0;
        float sc  = -FLT_MAX;
        if (lane < deg) {
            eid = sorted_eid[beg + lane];      // coalesced
            sc  = sorted_score[beg + lane];    // coalesced
        }
        float m = sc;
        #pragma unroll
        for (int off = 32; off; off >>= 1)
            m = fmaxf(m, __shfl_xor(m, off, 64));
        float exr = (lane < deg) ? expf(sc - m) : 0.f;
        float ds  = exr;
        #pragma unroll
        for (int off = 32; off; off >>= 1)
            ds += __shfl_xor(ds, off, 64);
        float inv = ds > 0.f ? 1.0f / ds : 0.0f;
        if (lane < deg) alpha[eid] = exr * inv;     // fused k_alpha
        // wave-uniform trip count; shfl src lane i = grp+4k <= 63, active.
        int iters = (deg + 3) >> 2;
        for (int k = 0; k < iters; ++k) {
            int i = grp + 4 * k;
            float ex = __shfl(exr, i, 64);
            int   e  = __shfl(eid, i, 64);
            if (i < deg) {
                float4 mm = M4[(size_t)e * 16 + sl];
                acc.x += ex * mm.x;
                acc.y += ex * mm.y;
                acc.z += ex * mm.z;
                acc.w += ex * mm.w;
            }
        }
        acc.x += __shfl_xor(acc.x, 16, 64);  acc.x += __shfl_xor(acc.x, 32, 64);
        acc.y += __shfl_xor(acc.y, 16, 64);  acc.y += __shfl_xor(acc.y, 32, 64);
        acc.z += __shfl_xor(acc.z, 16, 64);  acc.z += __shfl_xor(acc.z, 32, 64);
        acc.w += __shfl_xor(acc.w, 16, 64);  acc.w += __shfl_xor(acc.w, 32, 64);
        if (lane < 16) {
            float4 o;
            o.x = acc.x * inv; o.y = acc.y * inv;
            o.z = acc.z * inv; o.w = acc.w * inv;
            Mv4[(size_t)n * 16 + lane] = o;
        }
    } else {
        float m = -FLT_MAX;
        for (int i = beg + lane; i < end; i += 64)
            m = fmaxf(m, sorted_score[i]);
        #pragma unroll
        for (int off = 32; off; off >>= 1)
            m = fmaxf(m, __shfl_xor(m, off, 64));
        float dsum = 0.f;
        for (int i = beg + grp; i < end; i += 4) {
            int e = sorted_eid[i];
            float ex = expf(sorted_score[i] - m);
            if (sl == 0) dsum += ex;
            float4 mm = M4[(size_t)e * 16 + sl];
            acc.x += ex * mm.x;
            acc.y += ex * mm.y;
            acc.z += ex * mm.z;
            acc.w += ex * mm.w;
        }
        dsum += __shfl_xor(dsum, 16, 64);
        dsum += __shfl_xor(dsum, 32, 64);
        float dtot = __shfl(dsum, 0, 64);
        float inv = dtot > 0.f ? 1.0f / dtot : 0.0f;
        for (int i = beg + lane; i < end; i += 64) {
            alpha[sorted_eid[i]] = expf(sorted_score[i] - m) * inv;
        }
        acc.x += __shfl_xor(acc.x, 16, 64);  acc.x += __shfl_xor(acc.x, 32, 64);
        acc.y += __shfl_xor(acc.y, 16, 64);  acc.y += __shfl_xor(acc.y, 32, 64);
        acc.z += __shfl_xor(acc.z, 16, 64);  acc.z += __shfl_xor(acc.z, 32, 64);
        acc.w += __shfl_xor(acc.w, 16, 64);  acc.w += __shfl_xor(acc.w, 32, 64);
        if (lane < 16) {
            float4 o;
            o.x = acc.x * inv; o.y = acc.y * inv;
            o.z = acc.z * inv; o.w = acc.w * inv;
            Mv4[(size_t)n * 16 + lane] = o;
        }
    }
}

// ---------------------------------------------------------------------------
// K5: 16 lanes/edge. out = Mv[src] - alpha[rev] * M[rev]. Per-lane
// same-address scalar loads (HW broadcast). Nontemporal store so the 205MB
// out-stream doesn't evict M from L3.
__global__ void k_out(const float4* __restrict__ M4,
                      const float4* __restrict__ Mv4,
                      const float* __restrict__ alpha,
                      const int* __restrict__ src,
                      const int* __restrict__ rev,
                      f32x4* __restrict__ out4,
                      int E) {
    long long gid = (long long)blockIdx.x * blockDim.x + threadIdx.x;
    int e  = (int)(gid >> 4);
    int sl = (int)(gid & 15);
    if (e >= E) return;
    int s    = src[e];
    int r    = rev[e];
    float al = alpha[r];
    float4 mv = Mv4[(size_t)s * 16 + sl];
    float4 mr = M4[(size_t)r * 16 + sl];
    f32x4 o;
    o.x = mv.x - al * mr.x;
    o.y = mv.y - al * mr.y;
    o.z = mv.z - al * mr.z;
    o.w = mv.w - al * mr.w;
    __builtin_nontemporal_store(o, &out4[(size_t)e * 16 + sl]);
}

// ---------------------------------------------------------------------------
extern "C" void kernel_launch(void* const* d_in, const int* in_sizes, int n_in,
                              void* d_out, int out_size, void* d_ws, size_t ws_size,
                              hipStream_t stream) {
    const float* M  = (const float*)d_in[0];
    const float* a  = (const float*)d_in[1];
    const int* eidx = (const int*)d_in[2];   // [2, E] flat: src row, dest row
    const int* rev  = (const int*)d_in[3];
    const int N = 50000;
    const int E = in_sizes[3];

    const int* src  = eidx;
    const int* dest = eidx + E;

    // Workspace: Mv[N*64] | sorted_score[E] | alpha[E] | sorted_eid[E] |
    //            counts[N]+total[4] | offsets[N] | cursor[N]
    char* ws = (char*)d_ws;
    float* Mv           = (float*)ws; ws += (size_t)N * 64 * 4;
    float* sorted_score = (float*)ws; ws += (size_t)E * 4;
    float* alpha        = (float*)ws; ws += (size_t)E * 4;
    int*   sorted_eid   = (int*)ws;   ws += (size_t)E * 4;
    int*   counts       = (int*)ws;   ws += (size_t)(N + 4) * 4;  // +total
    int*   offsets      = (int*)ws;   ws += (size_t)N * 4;
    int*   cursor       = (int*)ws;   ws += (size_t)N * 4;
    int*   total        = counts + N;

    long long tE16 = (long long)E * 16;
    int blocksE16 = (int)((tE16 + THREADS - 1) / THREADS);
    int blocksE   = (E + THREADS - 1) / THREADS;
    int blocksN   = (N + THREADS - 1) / THREADS;
    int blocksN64 = (int)(((long long)N * 64 + THREADS - 1) / THREADS);
    int n4        = (N + 4) / 4;               // counts + total
    int blocksZ   = (n4 + THREADS - 1) / THREADS;

    k_zero<<<blocksZ, THREADS, 0, stream>>>((int4*)counts, n4);
    k_hist<<<blocksE, THREADS, 0, stream>>>(dest, counts, E);
    k_alloc<<<blocksN, THREADS, 0, stream>>>(counts, total, offsets, cursor, N);
    k_score_fill<<<blocksE16, THREADS, 0, stream>>>(
        (const float4*)M, (const float4*)a, dest, cursor,
        sorted_eid, sorted_score, E);
    k_aggregate<<<blocksN64, THREADS, 0, stream>>>(
        (const float4*)M, sorted_score, sorted_eid, offsets, counts,
        (float4*)Mv, alpha, N);
    k_out<<<blocksE16, THREADS, 0, stream>>>(
        (const float4*)M, (const float4*)Mv, alpha, src, rev,
        (f32x4*)d_out, E);
}